// Round 4
// baseline (42480.200 us; speedup 1.0000x reference)
//
#include <hip/hip_runtime.h>
#include <hip/hip_bf16.h>
#include <hip/hip_fp16.h>

// ---------------------------------------------------------------------------
// ModelInstructionAggregate: token-LSTM (batch 8192, T<=16) -> sequential
// instruction-LSTM (8192 steps, batch 1) -> Linear(256->1).
// Round 4: k_seq_lstm rebuilt on v_mfma_f32_16x16x32_f16.
//   Round-3 finding: VALU can't read AGPRs; 192 weight-half2/thread forced
//   AGPR churn (~+2000 instr/step) and the allocator ignored waves_per_eu.
//   MFMA reads A/B from AGPR or VGPR directly -> weights as B-fragments.
//   Wave w owns 64 gate rows: 4 N-tiles x 8 K-tiles = 32 MFMA/wave/step.
//   A = h broadcast to all 16 M-rows (A-frag depends only on lane-quad), so
//   every D element equals its column's gate value; C-init carries XI.
// ---------------------------------------------------------------------------

constexpr int H_ = 256;    // hidden
constexpr int T_ = 16;     // max token steps
constexpr int N_ = 8192;   // instructions
constexpr int BI = 16;     // instructions per block in batched kernels

typedef _Float16 half_t;
typedef half_t half2_t __attribute__((ext_vector_type(2)));
typedef half_t f16x8   __attribute__((ext_vector_type(8)));
typedef float  f32x4   __attribute__((ext_vector_type(4)));

#define MFMA16x16x32F16(a, b, c) __builtin_amdgcn_mfma_f32_16x16x32_f16((a), (b), (c), 0, 0, 0)

__device__ __forceinline__ float sigmoidf_(float x) {
    return 1.0f / (1.0f + __expf(-x));
}
__device__ __forceinline__ float tanhf_(float x) {
    return 2.0f / (1.0f + __expf(-2.0f * x)) - 1.0f;
}

// --------------------------- weight transposes -----------------------------
__global__ __launch_bounds__(256) void k_transpose_cat(
    const float* __restrict__ Wih, const float* __restrict__ Whh,
    float4* __restrict__ Wt)
{
    int tid = blockIdx.x * 256 + threadIdx.x;      // 1024 rows * 128 kb
    int kb = tid & 127, row = tid >> 7;
    float4 v = (kb < 64) ? ((const float4*)Wih)[row * 64 + kb]
                         : ((const float4*)Whh)[row * 64 + (kb - 64)];
    Wt[kb * 1024 + row] = v;
}

__global__ __launch_bounds__(256) void k_transpose_i(
    const float* __restrict__ Wsrc, float4* __restrict__ Wt)
{
    int tid = blockIdx.x * 256 + threadIdx.x;      // 1024 rows * 64 kb
    int kb = tid & 63, row = tid >> 6;
    Wt[kb * 1024 + row] = ((const float4*)Wsrc)[row * 64 + kb];
}

// ----------------------- phase 1: batched token LSTM -----------------------
__global__ __launch_bounds__(256, 4) void k_token_lstm(
    const float* __restrict__ tokens, const int* __restrict__ lengths,
    const float4* __restrict__ Wt,   // [128][1024] float4 (x-part then h-part)
    const float* __restrict__ bih, const float* __restrict__ bhh,
    float* __restrict__ embeds)      // [N_][H_]
{
    __shared__ __align__(16) float xs[BI][H_];
    __shared__ __align__(16) float hs[BI][H_];
    __shared__ __align__(16) float cs[BI][H_];
    __shared__ int len[BI];

    const int j = threadIdx.x;
    const int n0 = blockIdx.x * BI;
    if (j < BI) len[j] = lengths[n0 + j];
#pragma unroll
    for (int i = 0; i < BI; ++i) { hs[i][j] = 0.f; cs[i][j] = 0.f; }
    const float b0 = bih[j]       + bhh[j];
    const float b1 = bih[256 + j] + bhh[256 + j];
    const float b2 = bih[512 + j] + bhh[512 + j];
    const float b3 = bih[768 + j] + bhh[768 + j];
    __syncthreads();

    for (int t = 0; t < T_; ++t) {
#pragma unroll
        for (int q = 0; q < 4; ++q) {
            int idx = j + q * 256;
            int i = idx >> 6, e4 = idx & 63;
            ((float4*)xs)[i * 64 + e4] =
                ((const float4*)tokens)[((size_t)(n0 + i) * T_ + t) * 64 + e4];
        }
        __syncthreads();

        float a0[BI], a1[BI], a2[BI], a3[BI];
#pragma unroll
        for (int i = 0; i < BI; ++i) { a0[i] = 0.f; a1[i] = 0.f; a2[i] = 0.f; a3[i] = 0.f; }

        for (int kb = 0; kb < 64; ++kb) {
            float4 w0 = Wt[kb * 1024 + j];
            float4 w1 = Wt[kb * 1024 + 256 + j];
            float4 w2 = Wt[kb * 1024 + 512 + j];
            float4 w3 = Wt[kb * 1024 + 768 + j];
#pragma unroll
            for (int i = 0; i < BI; ++i) {
                float4 x4 = ((const float4*)xs)[i * 64 + kb];
                a0[i] += w0.x * x4.x + w0.y * x4.y + w0.z * x4.z + w0.w * x4.w;
                a1[i] += w1.x * x4.x + w1.y * x4.y + w1.z * x4.z + w1.w * x4.w;
                a2[i] += w2.x * x4.x + w2.y * x4.y + w2.z * x4.z + w2.w * x4.w;
                a3[i] += w3.x * x4.x + w3.y * x4.y + w3.z * x4.z + w3.w * x4.w;
            }
        }
        for (int kb = 0; kb < 64; ++kb) {
            float4 w0 = Wt[(64 + kb) * 1024 + j];
            float4 w1 = Wt[(64 + kb) * 1024 + 256 + j];
            float4 w2 = Wt[(64 + kb) * 1024 + 512 + j];
            float4 w3 = Wt[(64 + kb) * 1024 + 768 + j];
#pragma unroll
            for (int i = 0; i < BI; ++i) {
                float4 h4 = ((const float4*)hs)[i * 64 + kb];
                a0[i] += w0.x * h4.x + w0.y * h4.y + w0.z * h4.z + w0.w * h4.w;
                a1[i] += w1.x * h4.x + w1.y * h4.y + w1.z * h4.z + w1.w * h4.w;
                a2[i] += w2.x * h4.x + w2.y * h4.y + w2.z * h4.z + w2.w * h4.w;
                a3[i] += w3.x * h4.x + w3.y * h4.y + w3.z * h4.z + w3.w * h4.w;
            }
        }
        __syncthreads();

#pragma unroll
        for (int i = 0; i < BI; ++i) {
            if (t < len[i]) {
                float gi = sigmoidf_(a0[i] + b0);
                float gf = sigmoidf_(a1[i] + b1);
                float gg = tanhf_   (a2[i] + b2);
                float go = sigmoidf_(a3[i] + b3);
                float c2 = gf * cs[i][j] + gi * gg;
                cs[i][j] = c2;
                hs[i][j] = go * tanhf_(c2);
            }
        }
    }
#pragma unroll
    for (int i = 0; i < BI; ++i)
        embeds[(size_t)(n0 + i) * H_ + j] = hs[i][j];
}

// --------------------- phase 2a: XI = embeds @ Wih_i^T + b ------------------
__global__ __launch_bounds__(256, 4) void k_xi(
    const float* __restrict__ embeds, const float4* __restrict__ WiT, // [64][1024]
    const float* __restrict__ bih, const float* __restrict__ bhh,
    float* __restrict__ XI)          // [N_][1024]
{
    __shared__ __align__(16) float xs[BI][H_];
    const int j = threadIdx.x;
    const int n0 = blockIdx.x * BI;
#pragma unroll
    for (int q = 0; q < 4; ++q) {
        int idx = j + q * 256;
        int i = idx >> 6, e4 = idx & 63;
        ((float4*)xs)[i * 64 + e4] = ((const float4*)embeds)[(size_t)(n0 + i) * 64 + e4];
    }
    const float b0 = bih[j]       + bhh[j];
    const float b1 = bih[256 + j] + bhh[256 + j];
    const float b2 = bih[512 + j] + bhh[512 + j];
    const float b3 = bih[768 + j] + bhh[768 + j];
    __syncthreads();

    float a0[BI], a1[BI], a2[BI], a3[BI];
#pragma unroll
    for (int i = 0; i < BI; ++i) { a0[i] = 0.f; a1[i] = 0.f; a2[i] = 0.f; a3[i] = 0.f; }

    for (int kb = 0; kb < 64; ++kb) {
        float4 w0 = WiT[kb * 1024 + j];
        float4 w1 = WiT[kb * 1024 + 256 + j];
        float4 w2 = WiT[kb * 1024 + 512 + j];
        float4 w3 = WiT[kb * 1024 + 768 + j];
#pragma unroll
        for (int i = 0; i < BI; ++i) {
            float4 x4 = ((const float4*)xs)[i * 64 + kb];
            a0[i] += w0.x * x4.x + w0.y * x4.y + w0.z * x4.z + w0.w * x4.w;
            a1[i] += w1.x * x4.x + w1.y * x4.y + w1.z * x4.z + w1.w * x4.w;
            a2[i] += w2.x * x4.x + w2.y * x4.y + w2.z * x4.z + w2.w * x4.w;
            a3[i] += w3.x * x4.x + w3.y * x4.y + w3.z * x4.z + w3.w * x4.w;
        }
    }
#pragma unroll
    for (int i = 0; i < BI; ++i) {
        size_t base = (size_t)(n0 + i) * 1024;
        XI[base + j]       = a0[i] + b0;
        XI[base + 256 + j] = a1[i] + b1;
        XI[base + 512 + j] = a2[i] + b2;
        XI[base + 768 + j] = a3[i] + b3;
    }
}

// ----------------- phase 2b: sequential instruction LSTM (MFMA) ------------
// 1024 threads = 16 waves, 4/SIMD. Wave w owns gate rows [64w, 64w+64):
// 4 N-tiles x 8 K-tiles of v_mfma_f32_16x16x32_f16, weights resident as
// B-fragments (128 VGPRs/thread, loaded once). A = h replicated across all
// 16 M-rows (frag depends only on lane quad) -> every D element equals its
// column's gate; C-init carries XI (f32). Two barriers/step; c in VGPR.
__global__ __launch_bounds__(1024) void k_seq_lstm(
    const float* __restrict__ XI,    // [N_][1024]
    const float* __restrict__ Whh,   // [1024][256]
    float* __restrict__ outs)        // [N_][H_]
{
    __shared__ __align__(16) half_t hh[H_];      // h as f16 (512 B)
    __shared__ __align__(16) float  gates[1024]; // gate pre-activations

    const int tid  = threadIdx.x;
    const int lane = tid & 63;
    const int wave = tid >> 6;
    const int col  = lane & 15;        // N within tile / M row id
    const int quad = lane >> 4;        // k-subchunk selector
    const int gb   = wave * 64;        // first gate row owned by this wave

    // ---- one-time: load B-fragments (f16) for 4 N-tiles x 8 K-tiles ----
    // B[k = quad*8+e][n = col] = Whh[gate_row][k]
    f16x8 bfrag[4][8];
#pragma unroll
    for (int nt = 0; nt < 4; ++nt) {
        const float* wrow = Whh + (size_t)(gb + nt * 16 + col) * H_;
#pragma unroll
        for (int kt = 0; kt < 8; ++kt) {
            const float4 vA = *(const float4*)(wrow + kt * 32 + quad * 8);
            const float4 vB = *(const float4*)(wrow + kt * 32 + quad * 8 + 4);
            bfrag[nt][kt] = f16x8{(half_t)vA.x, (half_t)vA.y, (half_t)vA.z, (half_t)vA.w,
                                  (half_t)vB.x, (half_t)vB.y, (half_t)vB.z, (half_t)vB.w};
        }
    }

    if (tid < H_) {
        hh[tid] = (half_t)0.f;
    }
    float c = 0.f;                     // cell state, thread tid<256 owns c[tid]
    __syncthreads();

    // XI for step 0 (value depends only on col within each N-tile)
    float4 xi_cur;
    {
        const float* p = XI;
        xi_cur.x = p[gb + 0 * 16 + col];
        xi_cur.y = p[gb + 1 * 16 + col];
        xi_cur.z = p[gb + 2 * 16 + col];
        xi_cur.w = p[gb + 3 * 16 + col];
    }

    for (int n = 0; n < N_; ++n) {
        // prefetch next step's XI (hidden under this step's MFMA + barriers)
        float4 xi_nxt = {0.f, 0.f, 0.f, 0.f};
        if (n + 1 < N_) {
            const float* p = XI + (size_t)(n + 1) * 1024;
            xi_nxt.x = p[gb + 0 * 16 + col];
            xi_nxt.y = p[gb + 1 * 16 + col];
            xi_nxt.z = p[gb + 2 * 16 + col];
            xi_nxt.w = p[gb + 3 * 16 + col];
        }

        // A-fragments: h[kt*32 + quad*8 .. +8) as f16x8 (broadcast per quad)
        f16x8 afr[8];
#pragma unroll
        for (int kt = 0; kt < 8; ++kt)
            afr[kt] = *(const f16x8*)(hh + kt * 32 + quad * 8);

        // D = sum_k A_k * B_k + XI   (4 independent chains of depth 8)
        f32x4 D0 = {xi_cur.x, xi_cur.x, xi_cur.x, xi_cur.x};
        f32x4 D1 = {xi_cur.y, xi_cur.y, xi_cur.y, xi_cur.y};
        f32x4 D2 = {xi_cur.z, xi_cur.z, xi_cur.z, xi_cur.z};
        f32x4 D3 = {xi_cur.w, xi_cur.w, xi_cur.w, xi_cur.w};
#pragma unroll
        for (int kt = 0; kt < 8; ++kt) {
            D0 = MFMA16x16x32F16(afr[kt], bfrag[0][kt], D0);
            D1 = MFMA16x16x32F16(afr[kt], bfrag[1][kt], D1);
            D2 = MFMA16x16x32F16(afr[kt], bfrag[2][kt], D2);
            D3 = MFMA16x16x32F16(afr[kt], bfrag[3][kt], D3);
        }

        // extract row 0 (lanes 0-15, reg .x) -> gates in LDS
        if (lane < 16) {
            gates[gb +  0 + lane] = D0.x;
            gates[gb + 16 + lane] = D1.x;
            gates[gb + 32 + lane] = D2.x;
            gates[gb + 48 + lane] = D3.x;
        }
        __syncthreads();   // gates visible

        if (tid < H_) {
            float gi = sigmoidf_(gates[tid]);
            float gf = sigmoidf_(gates[256 + tid]);
            float gg = tanhf_   (gates[512 + tid]);
            float go = sigmoidf_(gates[768 + tid]);
            c = gf * c + gi * gg;
            float h2 = go * tanhf_(c);
            hh[tid] = (half_t)h2;
            outs[(size_t)n * H_ + tid] = h2;
        }
        __syncthreads();   // hh visible for next step's A-fragments
        xi_cur = xi_nxt;
    }
}

// ------------------------- final linear head -------------------------------
__global__ __launch_bounds__(256) void k_final(
    const float* __restrict__ outs, const float* __restrict__ Wl,
    const float* __restrict__ bl, float* __restrict__ y)
{
    const int lane = threadIdx.x & 63;
    const int g = threadIdx.x >> 6;
    const int n = blockIdx.x * 4 + g;
    const float* row = outs + (size_t)n * H_;
    float s = row[lane] * Wl[lane] + row[64 + lane] * Wl[64 + lane]
            + row[128 + lane] * Wl[128 + lane] + row[192 + lane] * Wl[192 + lane];
#pragma unroll
    for (int off = 32; off > 0; off >>= 1) s += __shfl_down(s, off, 64);
    if (lane == 0) y[n] = s + bl[0];
}

// ---------------------------------------------------------------------------
extern "C" void kernel_launch(void* const* d_in, const int* in_sizes, int n_in,
                              void* d_out, int out_size, void* d_ws, size_t ws_size,
                              hipStream_t stream)
{
    const float* tokens = (const float*)d_in[0];
    const int*   lengths= (const int*)  d_in[1];
    const float* Wih_t  = (const float*)d_in[2];
    const float* Whh_t  = (const float*)d_in[3];
    const float* bih_t  = (const float*)d_in[4];
    const float* bhh_t  = (const float*)d_in[5];
    const float* Wih_i  = (const float*)d_in[6];
    const float* Whh_i  = (const float*)d_in[7];
    const float* bih_i  = (const float*)d_in[8];
    const float* bhh_i  = (const float*)d_in[9];
    const float* Wl     = (const float*)d_in[10];
    const float* bl     = (const float*)d_in[11];
    float* out = (float*)d_out;

    char* ws = (char*)d_ws;
    float*  embeds = (float*) (ws);                                // 8 MB
    float*  XI     = (float*) (ws + (size_t)8  * 1024 * 1024);     // 32 MB
    float*  outs   = (float*) (ws + (size_t)40 * 1024 * 1024);     // 8 MB
    float4* WcatT  = (float4*)(ws + (size_t)48 * 1024 * 1024);     // 2 MB
    float4* WiT    = (float4*)(ws + (size_t)50 * 1024 * 1024);     // 1 MB

    k_transpose_cat<<<512,  256, 0, stream>>>(Wih_t, Whh_t, WcatT);
    k_transpose_i  <<<256,  256, 0, stream>>>(Wih_i, WiT);
    k_token_lstm   <<<512,  256, 0, stream>>>(tokens, lengths, WcatT, bih_t, bhh_t, embeds);
    k_xi           <<<512,  256, 0, stream>>>(embeds, WiT, bih_i, bhh_i, XI);
    k_seq_lstm     <<<1,   1024, 0, stream>>>(XI, Whh_i, outs);
    k_final        <<<2048, 256, 0, stream>>>(outs, Wl, bl, out);
}

// Round 5
// 20077.841 us; speedup vs baseline: 2.1158x; 2.1158x over previous
//
#include <hip/hip_runtime.h>
#include <hip/hip_bf16.h>
#include <hip/hip_fp16.h>

// ---------------------------------------------------------------------------
// ModelInstructionAggregate: token-LSTM (batch 8192, T<=16) -> sequential
// instruction-LSTM (8192 steps, batch 1) -> Linear(256->1).
// Round 5: k_seq_lstm = MFMA with the RIGHT resource shape.
//   Round-4 autopsy: 1024 thr -> 4 waves/SIMD -> 128 unified regs; bfrag
//   (128) forced a scratch spill re-read every step (VGPR_Count=64). Fix:
//   512 thr -> 2 waves/SIMD -> 256 unified regs. 6/8 K-tiles resident
//   (192 regs, AGPR-eligible: MFMA reads AGPRs, unlike round-3's v_dot2),
//   2/8 streamed from 128 KB LDS as dense ds_read_b128.
//   Wave w owns units [32w,32w+32) x all 4 gates (8 N-tiles) -> gate
//   nonlinearity entirely in-wave; h double-buffered -> 1 barrier/step.
//   XI added post-MFMA (loads hide under the chain; no prefetch regs).
// ---------------------------------------------------------------------------

constexpr int H_ = 256;    // hidden
constexpr int T_ = 16;     // max token steps
constexpr int N_ = 8192;   // instructions
constexpr int BI = 16;     // instructions per block in batched kernels

typedef _Float16 half_t;
typedef half_t half2_t __attribute__((ext_vector_type(2)));
typedef half_t f16x8   __attribute__((ext_vector_type(8)));
typedef float  f32x4   __attribute__((ext_vector_type(4)));

#define MFMA16x16x32F16(a, b, c) __builtin_amdgcn_mfma_f32_16x16x32_f16((a), (b), (c), 0, 0, 0)

__device__ __forceinline__ float sigmoidf_(float x) {
    return 1.0f / (1.0f + __expf(-x));
}
__device__ __forceinline__ float tanhf_(float x) {
    return 2.0f / (1.0f + __expf(-2.0f * x)) - 1.0f;
}

// --------------------------- weight transposes -----------------------------
__global__ __launch_bounds__(256) void k_transpose_cat(
    const float* __restrict__ Wih, const float* __restrict__ Whh,
    float4* __restrict__ Wt)
{
    int tid = blockIdx.x * 256 + threadIdx.x;      // 1024 rows * 128 kb
    int kb = tid & 127, row = tid >> 7;
    float4 v = (kb < 64) ? ((const float4*)Wih)[row * 64 + kb]
                         : ((const float4*)Whh)[row * 64 + (kb - 64)];
    Wt[kb * 1024 + row] = v;
}

__global__ __launch_bounds__(256) void k_transpose_i(
    const float* __restrict__ Wsrc, float4* __restrict__ Wt)
{
    int tid = blockIdx.x * 256 + threadIdx.x;      // 1024 rows * 64 kb
    int kb = tid & 63, row = tid >> 6;
    Wt[kb * 1024 + row] = ((const float4*)Wsrc)[row * 64 + kb];
}

// ----------------------- phase 1: batched token LSTM -----------------------
__global__ __launch_bounds__(256, 4) void k_token_lstm(
    const float* __restrict__ tokens, const int* __restrict__ lengths,
    const float4* __restrict__ Wt,   // [128][1024] float4 (x-part then h-part)
    const float* __restrict__ bih, const float* __restrict__ bhh,
    float* __restrict__ embeds)      // [N_][H_]
{
    __shared__ __align__(16) float xs[BI][H_];
    __shared__ __align__(16) float hs[BI][H_];
    __shared__ __align__(16) float cs[BI][H_];
    __shared__ int len[BI];

    const int j = threadIdx.x;
    const int n0 = blockIdx.x * BI;
    if (j < BI) len[j] = lengths[n0 + j];
#pragma unroll
    for (int i = 0; i < BI; ++i) { hs[i][j] = 0.f; cs[i][j] = 0.f; }
    const float b0 = bih[j]       + bhh[j];
    const float b1 = bih[256 + j] + bhh[256 + j];
    const float b2 = bih[512 + j] + bhh[512 + j];
    const float b3 = bih[768 + j] + bhh[768 + j];
    __syncthreads();

    for (int t = 0; t < T_; ++t) {
#pragma unroll
        for (int q = 0; q < 4; ++q) {
            int idx = j + q * 256;
            int i = idx >> 6, e4 = idx & 63;
            ((float4*)xs)[i * 64 + e4] =
                ((const float4*)tokens)[((size_t)(n0 + i) * T_ + t) * 64 + e4];
        }
        __syncthreads();

        float a0[BI], a1[BI], a2[BI], a3[BI];
#pragma unroll
        for (int i = 0; i < BI; ++i) { a0[i] = 0.f; a1[i] = 0.f; a2[i] = 0.f; a3[i] = 0.f; }

        for (int kb = 0; kb < 64; ++kb) {
            float4 w0 = Wt[kb * 1024 + j];
            float4 w1 = Wt[kb * 1024 + 256 + j];
            float4 w2 = Wt[kb * 1024 + 512 + j];
            float4 w3 = Wt[kb * 1024 + 768 + j];
#pragma unroll
            for (int i = 0; i < BI; ++i) {
                float4 x4 = ((const float4*)xs)[i * 64 + kb];
                a0[i] += w0.x * x4.x + w0.y * x4.y + w0.z * x4.z + w0.w * x4.w;
                a1[i] += w1.x * x4.x + w1.y * x4.y + w1.z * x4.z + w1.w * x4.w;
                a2[i] += w2.x * x4.x + w2.y * x4.y + w2.z * x4.z + w2.w * x4.w;
                a3[i] += w3.x * x4.x + w3.y * x4.y + w3.z * x4.z + w3.w * x4.w;
            }
        }
        for (int kb = 0; kb < 64; ++kb) {
            float4 w0 = Wt[(64 + kb) * 1024 + j];
            float4 w1 = Wt[(64 + kb) * 1024 + 256 + j];
            float4 w2 = Wt[(64 + kb) * 1024 + 512 + j];
            float4 w3 = Wt[(64 + kb) * 1024 + 768 + j];
#pragma unroll
            for (int i = 0; i < BI; ++i) {
                float4 h4 = ((const float4*)hs)[i * 64 + kb];
                a0[i] += w0.x * h4.x + w0.y * h4.y + w0.z * h4.z + w0.w * h4.w;
                a1[i] += w1.x * h4.x + w1.y * h4.y + w1.z * h4.z + w1.w * h4.w;
                a2[i] += w2.x * h4.x + w2.y * h4.y + w2.z * h4.z + w2.w * h4.w;
                a3[i] += w3.x * h4.x + w3.y * h4.y + w3.z * h4.z + w3.w * h4.w;
            }
        }
        __syncthreads();

#pragma unroll
        for (int i = 0; i < BI; ++i) {
            if (t < len[i]) {
                float gi = sigmoidf_(a0[i] + b0);
                float gf = sigmoidf_(a1[i] + b1);
                float gg = tanhf_   (a2[i] + b2);
                float go = sigmoidf_(a3[i] + b3);
                float c2 = gf * cs[i][j] + gi * gg;
                cs[i][j] = c2;
                hs[i][j] = go * tanhf_(c2);
            }
        }
    }
#pragma unroll
    for (int i = 0; i < BI; ++i)
        embeds[(size_t)(n0 + i) * H_ + j] = hs[i][j];
}

// --------------------- phase 2a: XI = embeds @ Wih_i^T + b ------------------
__global__ __launch_bounds__(256, 4) void k_xi(
    const float* __restrict__ embeds, const float4* __restrict__ WiT, // [64][1024]
    const float* __restrict__ bih, const float* __restrict__ bhh,
    float* __restrict__ XI)          // [N_][1024]
{
    __shared__ __align__(16) float xs[BI][H_];
    const int j = threadIdx.x;
    const int n0 = blockIdx.x * BI;
#pragma unroll
    for (int q = 0; q < 4; ++q) {
        int idx = j + q * 256;
        int i = idx >> 6, e4 = idx & 63;
        ((float4*)xs)[i * 64 + e4] = ((const float4*)embeds)[(size_t)(n0 + i) * 64 + e4];
    }
    const float b0 = bih[j]       + bhh[j];
    const float b1 = bih[256 + j] + bhh[256 + j];
    const float b2 = bih[512 + j] + bhh[512 + j];
    const float b3 = bih[768 + j] + bhh[768 + j];
    __syncthreads();

    float a0[BI], a1[BI], a2[BI], a3[BI];
#pragma unroll
    for (int i = 0; i < BI; ++i) { a0[i] = 0.f; a1[i] = 0.f; a2[i] = 0.f; a3[i] = 0.f; }

    for (int kb = 0; kb < 64; ++kb) {
        float4 w0 = WiT[kb * 1024 + j];
        float4 w1 = WiT[kb * 1024 + 256 + j];
        float4 w2 = WiT[kb * 1024 + 512 + j];
        float4 w3 = WiT[kb * 1024 + 768 + j];
#pragma unroll
        for (int i = 0; i < BI; ++i) {
            float4 x4 = ((const float4*)xs)[i * 64 + kb];
            a0[i] += w0.x * x4.x + w0.y * x4.y + w0.z * x4.z + w0.w * x4.w;
            a1[i] += w1.x * x4.x + w1.y * x4.y + w1.z * x4.z + w1.w * x4.w;
            a2[i] += w2.x * x4.x + w2.y * x4.y + w2.z * x4.z + w2.w * x4.w;
            a3[i] += w3.x * x4.x + w3.y * x4.y + w3.z * x4.z + w3.w * x4.w;
        }
    }
#pragma unroll
    for (int i = 0; i < BI; ++i) {
        size_t base = (size_t)(n0 + i) * 1024;
        XI[base + j]       = a0[i] + b0;
        XI[base + 256 + j] = a1[i] + b1;
        XI[base + 512 + j] = a2[i] + b2;
        XI[base + 768 + j] = a3[i] + b3;
    }
}

// ----------------- phase 2b: sequential instruction LSTM (MFMA) ------------
// 512 threads = 8 waves, 2/SIMD (256 unified regs/thread).
// Wave w owns units [32w,32w+32): 8 N-tiles = {gate g, sub s} with rows
// 256g + 32w + 16s + [0,16). K: kt 0..5 resident B-frags (192 regs, AGPR ok),
// kt 6..7 streamed from LDS (128 KB, dense b128). h f16 double-buffered in
// LDS -> 1 barrier/step. Gates stay in-register (all 4 gates per unit land
// in the same lane); c in VGPR (x4 quad-redundant).
constexpr int SMEM_SEQ = 8192 * 16 /*tail*/ + 2 * 256 * 2 /*hh dbuf*/; // 132096

__global__ __launch_bounds__(512, 2) void k_seq_lstm(
    const float* __restrict__ XI,    // [N_][1024]
    const float* __restrict__ Whh,   // [1024][256]
    float* __restrict__ outs)        // [N_][H_]
{
    extern __shared__ __align__(16) char smem[];
    uint4*  tail = (uint4*)smem;                     // [quad][ktp][row] 16B chunks
    half_t* hhb  = (half_t*)(smem + 8192 * 16);      // [2][256] h double buffer

    const int tid  = threadIdx.x;
    const int lane = tid & 63;
    const int wave = tid >> 6;
    const int col  = lane & 15;
    const int quad = lane >> 4;
    const int rbase = wave * 32;     // first unit owned by this wave

    // ---- one-time: resident B-fragments, t = g*2+s, kt 0..5 ----
    // B[k=quad*8+j][n=col] = Whh[256g + 32w + 16s + col][kt*32 + quad*8 + j]
    f16x8 bfrag[8][6];
#pragma unroll
    for (int t = 0; t < 8; ++t) {
        const int row = 256 * (t >> 1) + rbase + 16 * (t & 1) + col;
        const float* wrow = Whh + (size_t)row * H_ + quad * 8;
#pragma unroll
        for (int kt = 0; kt < 6; ++kt) {
            const float4 vA = *(const float4*)(wrow + kt * 32);
            const float4 vB = *(const float4*)(wrow + kt * 32 + 4);
            bfrag[t][kt] = f16x8{(half_t)vA.x, (half_t)vA.y, (half_t)vA.z, (half_t)vA.w,
                                 (half_t)vB.x, (half_t)vB.y, (half_t)vB.z, (half_t)vB.w};
        }
    }

    // ---- one-time: stage k 192..255 into LDS ----
    // chunk (ktp, row, q) -> uint4 index q*2048 + ktp*1024 + row
    // (byte addr = q*32768 + ktp*16384 + row*16; reader keeps ktp in the
    //  ds offset field, quad-groups read 256 B dense -> conflict-free)
#pragma unroll
    for (int it = 0; it < 16; ++it) {
        int cid = it * 512 + tid;
        int q   = cid & 3;
        int row = (cid >> 2) & 1023;
        int ktp = cid >> 12;
        const float* src = Whh + (size_t)row * H_ + 192 + ktp * 32 + q * 8;
        const float4 vA = *(const float4*)(src);
        const float4 vB = *(const float4*)(src + 4);
        f16x8 v = f16x8{(half_t)vA.x, (half_t)vA.y, (half_t)vA.z, (half_t)vA.w,
                        (half_t)vB.x, (half_t)vB.y, (half_t)vB.z, (half_t)vB.w};
        tail[q * 2048 + ktp * 1024 + row] = __builtin_bit_cast(uint4, v);
    }

    if (tid < H_) hhb[tid] = (half_t)0.f;   // h buffer 0 = step-0 input
    float c0 = 0.f, c1 = 0.f;               // cell state (x4 quad-redundant)
    __syncthreads();

    const int u0 = rbase + col, u1 = rbase + 16 + col;

    for (int n = 0; n < N_; ++n) {
        const half_t* hcur = hhb + (n & 1) * 256;

        // XI loads issue now, consumed after the MFMA chain (latency hidden)
        float xi[8];
#pragma unroll
        for (int t = 0; t < 8; ++t)
            xi[t] = XI[(size_t)n * 1024 + 256 * (t >> 1) + rbase + 16 * (t & 1) + col];

        f32x4 D[8];
#pragma unroll
        for (int t = 0; t < 8; ++t) D[t] = f32x4{0.f, 0.f, 0.f, 0.f};

#pragma unroll
        for (int kt = 0; kt < 6; ++kt) {     // resident K-tiles
            f16x8 a = *(const f16x8*)(hcur + kt * 32 + quad * 8);
#pragma unroll
            for (int t = 0; t < 8; ++t)
                D[t] = MFMA16x16x32F16(a, bfrag[t][kt], D[t]);
        }
#pragma unroll
        for (int ktp = 0; ktp < 2; ++ktp) {  // streamed K-tiles (LDS b128)
            f16x8 a = *(const f16x8*)(hcur + 192 + ktp * 32 + quad * 8);
#pragma unroll
            for (int t = 0; t < 8; ++t) {
                const int row = 256 * (t >> 1) + rbase + 16 * (t & 1) + col;
                f16x8 b = __builtin_bit_cast(f16x8, tail[quad * 2048 + ktp * 1024 + row]);
                D[t] = MFMA16x16x32F16(a, b, D[t]);
            }
        }

        // gates (rows of D identical; .x works for every lane)
        // t = g*2+s: unit u0 uses t{0,2,4,6}, u1 uses t{1,3,5,7}
        float gi0 = sigmoidf_(D[0].x + xi[0]);
        float gf0 = sigmoidf_(D[2].x + xi[2]);
        float gg0 = tanhf_   (D[4].x + xi[4]);
        float go0 = sigmoidf_(D[6].x + xi[6]);
        c0 = gf0 * c0 + gi0 * gg0;
        float h0 = go0 * tanhf_(c0);

        float gi1 = sigmoidf_(D[1].x + xi[1]);
        float gf1 = sigmoidf_(D[3].x + xi[3]);
        float gg1 = tanhf_   (D[5].x + xi[5]);
        float go1 = sigmoidf_(D[7].x + xi[7]);
        c1 = gf1 * c1 + gi1 * gg1;
        float h1 = go1 * tanhf_(c1);

        half_t* hnxt = hhb + ((n + 1) & 1) * 256;
        if (quad == 0) {
            hnxt[u0] = (half_t)h0;
            hnxt[u1] = (half_t)h1;
            outs[(size_t)n * H_ + u0] = h0;
            outs[(size_t)n * H_ + u1] = h1;
        }
        __syncthreads();   // h(n+1) visible; other buffer free for writing
    }
}

// ------------------------- final linear head -------------------------------
__global__ __launch_bounds__(256) void k_final(
    const float* __restrict__ outs, const float* __restrict__ Wl,
    const float* __restrict__ bl, float* __restrict__ y)
{
    const int lane = threadIdx.x & 63;
    const int g = threadIdx.x >> 6;
    const int n = blockIdx.x * 4 + g;
    const float* row = outs + (size_t)n * H_;
    float s = row[lane] * Wl[lane] + row[64 + lane] * Wl[64 + lane]
            + row[128 + lane] * Wl[128 + lane] + row[192 + lane] * Wl[192 + lane];
#pragma unroll
    for (int off = 32; off > 0; off >>= 1) s += __shfl_down(s, off, 64);
    if (lane == 0) y[n] = s + bl[0];
}

// ---------------------------------------------------------------------------
extern "C" void kernel_launch(void* const* d_in, const int* in_sizes, int n_in,
                              void* d_out, int out_size, void* d_ws, size_t ws_size,
                              hipStream_t stream)
{
    const float* tokens = (const float*)d_in[0];
    const int*   lengths= (const int*)  d_in[1];
    const float* Wih_t  = (const float*)d_in[2];
    const float* Whh_t  = (const float*)d_in[3];
    const float* bih_t  = (const float*)d_in[4];
    const float* bhh_t  = (const float*)d_in[5];
    const float* Wih_i  = (const float*)d_in[6];
    const float* Whh_i  = (const float*)d_in[7];
    const float* bih_i  = (const float*)d_in[8];
    const float* bhh_i  = (const float*)d_in[9];
    const float* Wl     = (const float*)d_in[10];
    const float* bl     = (const float*)d_in[11];
    float* out = (float*)d_out;

    char* ws = (char*)d_ws;
    float*  embeds = (float*) (ws);                                // 8 MB
    float*  XI     = (float*) (ws + (size_t)8  * 1024 * 1024);     // 32 MB
    float*  outs   = (float*) (ws + (size_t)40 * 1024 * 1024);     // 8 MB
    float4* WcatT  = (float4*)(ws + (size_t)48 * 1024 * 1024);     // 2 MB
    float4* WiT    = (float4*)(ws + (size_t)50 * 1024 * 1024);     // 1 MB

    (void)hipFuncSetAttribute((const void*)k_seq_lstm,
        hipFuncAttributeMaxDynamicSharedMemorySize, SMEM_SEQ);

    k_transpose_cat<<<512,  256, 0, stream>>>(Wih_t, Whh_t, WcatT);
    k_transpose_i  <<<256,  256, 0, stream>>>(Wih_i, WiT);
    k_token_lstm   <<<512,  256, 0, stream>>>(tokens, lengths, WcatT, bih_t, bhh_t, embeds);
    k_xi           <<<512,  256, 0, stream>>>(embeds, WiT, bih_i, bhh_i, XI);
    k_seq_lstm     <<<1,    512, SMEM_SEQ, stream>>>(XI, Whh_i, outs);
    k_final        <<<2048, 256, 0, stream>>>(outs, Wl, bl, out);
}

// Round 6
// 19583.327 us; speedup vs baseline: 2.1692x; 1.0253x over previous
//
#include <hip/hip_runtime.h>
#include <hip/hip_bf16.h>
#include <hip/hip_fp16.h>

// ---------------------------------------------------------------------------
// ModelInstructionAggregate: token-LSTM (batch 8192, T<=16) -> sequential
// instruction-LSTM (8192 steps, batch 1) -> Linear(256->1).
// Round 6: fit k_seq_lstm's register budget FOR REAL.
//   Round-5 autopsy: bfrag 192 + D 32 + misc ~= 270 > 256 -> allocator split
//   bfrag across the AGPR/arch boundary + spilled (VALUBusy 41% on-CU of
//   moves). Fix: D[8]->D[4] via two half-passes (stash 4 scalars), XI folded
//   into accumulator init. Peak ~= 192 AGPR + ~58 arch <= 256.
//   Independent change: k_token_lstm BI 16->8, grid 1024 (4 blocks/CU, 2x
//   waves for the VALU-bound fp32 GEMM).
// ---------------------------------------------------------------------------

constexpr int H_ = 256;    // hidden
constexpr int T_ = 16;     // max token steps
constexpr int N_ = 8192;   // instructions
constexpr int BI = 8;      // instructions per block in k_token_lstm
constexpr int BX = 16;     // instructions per block in k_xi

typedef _Float16 half_t;
typedef half_t half2_t __attribute__((ext_vector_type(2)));
typedef half_t f16x8   __attribute__((ext_vector_type(8)));
typedef float  f32x4   __attribute__((ext_vector_type(4)));

#define MFMA16x16x32F16(a, b, c) __builtin_amdgcn_mfma_f32_16x16x32_f16((a), (b), (c), 0, 0, 0)

__device__ __forceinline__ float sigmoidf_(float x) {
    return 1.0f / (1.0f + __expf(-x));
}
__device__ __forceinline__ float tanhf_(float x) {
    return 2.0f / (1.0f + __expf(-2.0f * x)) - 1.0f;
}

// --------------------------- weight transposes -----------------------------
__global__ __launch_bounds__(256) void k_transpose_cat(
    const float* __restrict__ Wih, const float* __restrict__ Whh,
    float4* __restrict__ Wt)
{
    int tid = blockIdx.x * 256 + threadIdx.x;      // 1024 rows * 128 kb
    int kb = tid & 127, row = tid >> 7;
    float4 v = (kb < 64) ? ((const float4*)Wih)[row * 64 + kb]
                         : ((const float4*)Whh)[row * 64 + (kb - 64)];
    Wt[kb * 1024 + row] = v;
}

__global__ __launch_bounds__(256) void k_transpose_i(
    const float* __restrict__ Wsrc, float4* __restrict__ Wt)
{
    int tid = blockIdx.x * 256 + threadIdx.x;      // 1024 rows * 64 kb
    int kb = tid & 63, row = tid >> 6;
    Wt[kb * 1024 + row] = ((const float4*)Wsrc)[row * 64 + kb];
}

// ----------------------- phase 1: batched token LSTM -----------------------
// BI=8 instructions/block, 1024 blocks -> 4 blocks/CU (16 waves/CU).
__global__ __launch_bounds__(256, 4) void k_token_lstm(
    const float* __restrict__ tokens, const int* __restrict__ lengths,
    const float4* __restrict__ Wt,   // [128][1024] float4 (x-part then h-part)
    const float* __restrict__ bih, const float* __restrict__ bhh,
    float* __restrict__ embeds)      // [N_][H_]
{
    __shared__ __align__(16) float xs[BI][H_];
    __shared__ __align__(16) float hs[BI][H_];
    __shared__ __align__(16) float cs[BI][H_];
    __shared__ int len[BI];

    const int j = threadIdx.x;
    const int n0 = blockIdx.x * BI;
    if (j < BI) len[j] = lengths[n0 + j];
#pragma unroll
    for (int i = 0; i < BI; ++i) { hs[i][j] = 0.f; cs[i][j] = 0.f; }
    const float b0 = bih[j]       + bhh[j];
    const float b1 = bih[256 + j] + bhh[256 + j];
    const float b2 = bih[512 + j] + bhh[512 + j];
    const float b3 = bih[768 + j] + bhh[768 + j];
    __syncthreads();

    for (int t = 0; t < T_; ++t) {
#pragma unroll
        for (int q = 0; q < 2; ++q) {          // 8 instr * 64 float4 = 512
            int idx = j + q * 256;
            int i = idx >> 6, e4 = idx & 63;
            ((float4*)xs)[i * 64 + e4] =
                ((const float4*)tokens)[((size_t)(n0 + i) * T_ + t) * 64 + e4];
        }
        __syncthreads();

        float a0[BI], a1[BI], a2[BI], a3[BI];
#pragma unroll
        for (int i = 0; i < BI; ++i) { a0[i] = 0.f; a1[i] = 0.f; a2[i] = 0.f; a3[i] = 0.f; }

        for (int kb = 0; kb < 64; ++kb) {
            float4 w0 = Wt[kb * 1024 + j];
            float4 w1 = Wt[kb * 1024 + 256 + j];
            float4 w2 = Wt[kb * 1024 + 512 + j];
            float4 w3 = Wt[kb * 1024 + 768 + j];
#pragma unroll
            for (int i = 0; i < BI; ++i) {
                float4 x4 = ((const float4*)xs)[i * 64 + kb];
                a0[i] += w0.x * x4.x + w0.y * x4.y + w0.z * x4.z + w0.w * x4.w;
                a1[i] += w1.x * x4.x + w1.y * x4.y + w1.z * x4.z + w1.w * x4.w;
                a2[i] += w2.x * x4.x + w2.y * x4.y + w2.z * x4.z + w2.w * x4.w;
                a3[i] += w3.x * x4.x + w3.y * x4.y + w3.z * x4.z + w3.w * x4.w;
            }
        }
        for (int kb = 0; kb < 64; ++kb) {
            float4 w0 = Wt[(64 + kb) * 1024 + j];
            float4 w1 = Wt[(64 + kb) * 1024 + 256 + j];
            float4 w2 = Wt[(64 + kb) * 1024 + 512 + j];
            float4 w3 = Wt[(64 + kb) * 1024 + 768 + j];
#pragma unroll
            for (int i = 0; i < BI; ++i) {
                float4 h4 = ((const float4*)hs)[i * 64 + kb];
                a0[i] += w0.x * h4.x + w0.y * h4.y + w0.z * h4.z + w0.w * h4.w;
                a1[i] += w1.x * h4.x + w1.y * h4.y + w1.z * h4.z + w1.w * h4.w;
                a2[i] += w2.x * h4.x + w2.y * h4.y + w2.z * h4.z + w2.w * h4.w;
                a3[i] += w3.x * h4.x + w3.y * h4.y + w3.z * h4.z + w3.w * h4.w;
            }
        }
        __syncthreads();

#pragma unroll
        for (int i = 0; i < BI; ++i) {
            if (t < len[i]) {
                float gi = sigmoidf_(a0[i] + b0);
                float gf = sigmoidf_(a1[i] + b1);
                float gg = tanhf_   (a2[i] + b2);
                float go = sigmoidf_(a3[i] + b3);
                float c2 = gf * cs[i][j] + gi * gg;
                cs[i][j] = c2;
                hs[i][j] = go * tanhf_(c2);
            }
        }
    }
#pragma unroll
    for (int i = 0; i < BI; ++i)
        embeds[(size_t)(n0 + i) * H_ + j] = hs[i][j];
}

// --------------------- phase 2a: XI = embeds @ Wih_i^T + b ------------------
__global__ __launch_bounds__(256, 4) void k_xi(
    const float* __restrict__ embeds, const float4* __restrict__ WiT, // [64][1024]
    const float* __restrict__ bih, const float* __restrict__ bhh,
    float* __restrict__ XI)          // [N_][1024]
{
    __shared__ __align__(16) float xs[BX][H_];
    const int j = threadIdx.x;
    const int n0 = blockIdx.x * BX;
#pragma unroll
    for (int q = 0; q < 4; ++q) {
        int idx = j + q * 256;
        int i = idx >> 6, e4 = idx & 63;
        ((float4*)xs)[i * 64 + e4] = ((const float4*)embeds)[(size_t)(n0 + i) * 64 + e4];
    }
    const float b0 = bih[j]       + bhh[j];
    const float b1 = bih[256 + j] + bhh[256 + j];
    const float b2 = bih[512 + j] + bhh[512 + j];
    const float b3 = bih[768 + j] + bhh[768 + j];
    __syncthreads();

    float a0[BX], a1[BX], a2[BX], a3[BX];
#pragma unroll
    for (int i = 0; i < BX; ++i) { a0[i] = 0.f; a1[i] = 0.f; a2[i] = 0.f; a3[i] = 0.f; }

    for (int kb = 0; kb < 64; ++kb) {
        float4 w0 = WiT[kb * 1024 + j];
        float4 w1 = WiT[kb * 1024 + 256 + j];
        float4 w2 = WiT[kb * 1024 + 512 + j];
        float4 w3 = WiT[kb * 1024 + 768 + j];
#pragma unroll
        for (int i = 0; i < BX; ++i) {
            float4 x4 = ((const float4*)xs)[i * 64 + kb];
            a0[i] += w0.x * x4.x + w0.y * x4.y + w0.z * x4.z + w0.w * x4.w;
            a1[i] += w1.x * x4.x + w1.y * x4.y + w1.z * x4.z + w1.w * x4.w;
            a2[i] += w2.x * x4.x + w2.y * x4.y + w2.z * x4.z + w2.w * x4.w;
            a3[i] += w3.x * x4.x + w3.y * x4.y + w3.z * x4.z + w3.w * x4.w;
        }
    }
#pragma unroll
    for (int i = 0; i < BX; ++i) {
        size_t base = (size_t)(n0 + i) * 1024;
        XI[base + j]       = a0[i] + b0;
        XI[base + 256 + j] = a1[i] + b1;
        XI[base + 512 + j] = a2[i] + b2;
        XI[base + 768 + j] = a3[i] + b3;
    }
}

// ----------------- phase 2b: sequential instruction LSTM (MFMA) ------------
// 512 threads = 8 waves, 2/SIMD (256 unified regs/thread).
// Wave w owns units [32w,32w+32) x 4 gates = 8 N-tiles, processed as TWO
// half-passes of 4 tiles (D[4]=16 regs; stash 4 scalars between) so the
// peak register need is bfrag 192 (AGPR) + ~58 arch <= 256. XI enters via
// accumulator init. kt 0..5 resident, kt 6..7 streamed from 128 KB LDS.
// h f16 double-buffered in LDS -> 1 barrier/step.
constexpr int SMEM_SEQ = 8192 * 16 /*tail*/ + 2 * 256 * 2 /*hh dbuf*/; // 132096

__global__ __launch_bounds__(512, 2) void k_seq_lstm(
    const float* __restrict__ XI,    // [N_][1024]
    const float* __restrict__ Whh,   // [1024][256]
    float* __restrict__ outs)        // [N_][H_]
{
    extern __shared__ __align__(16) char smem[];
    uint4*  tail = (uint4*)smem;                     // [quad][ktp][row] 16B chunks
    half_t* hhb  = (half_t*)(smem + 8192 * 16);      // [2][256] h double buffer

    const int tid  = threadIdx.x;
    const int lane = tid & 63;
    const int wave = tid >> 6;
    const int col  = lane & 15;
    const int quad = lane >> 4;
    const int rbase = wave * 32;     // first unit owned by this wave

    // ---- one-time: resident B-fragments, t = g*2+s, kt 0..5 ----
    f16x8 bfrag[8][6];
#pragma unroll
    for (int t = 0; t < 8; ++t) {
        const int row = 256 * (t >> 1) + rbase + 16 * (t & 1) + col;
        const float* wrow = Whh + (size_t)row * H_ + quad * 8;
#pragma unroll
        for (int kt = 0; kt < 6; ++kt) {
            const float4 vA = *(const float4*)(wrow + kt * 32);
            const float4 vB = *(const float4*)(wrow + kt * 32 + 4);
            bfrag[t][kt] = f16x8{(half_t)vA.x, (half_t)vA.y, (half_t)vA.z, (half_t)vA.w,
                                 (half_t)vB.x, (half_t)vB.y, (half_t)vB.z, (half_t)vB.w};
        }
    }

    // ---- one-time: stage k 192..255 into LDS (layout verified conflict-free
    //      in round 5: SQ_LDS_BANK_CONFLICT ~= 0) ----
#pragma unroll
    for (int it = 0; it < 16; ++it) {
        int cid = it * 512 + tid;
        int q   = cid & 3;
        int row = (cid >> 2) & 1023;
        int ktp = cid >> 12;
        const float* src = Whh + (size_t)row * H_ + 192 + ktp * 32 + q * 8;
        const float4 vA = *(const float4*)(src);
        const float4 vB = *(const float4*)(src + 4);
        f16x8 v = f16x8{(half_t)vA.x, (half_t)vA.y, (half_t)vA.z, (half_t)vA.w,
                        (half_t)vB.x, (half_t)vB.y, (half_t)vB.z, (half_t)vB.w};
        tail[q * 2048 + ktp * 1024 + row] = __builtin_bit_cast(uint4, v);
    }

    if (tid < H_) hhb[tid] = (half_t)0.f;   // h buffer 0 = step-0 input
    float c0 = 0.f, c1 = 0.f;               // cell state (x4 quad-redundant)
    __syncthreads();

    const int u0 = rbase + col, u1 = rbase + 16 + col;

    // XI for step 0
    float xi_cur[8];
#pragma unroll
    for (int t = 0; t < 8; ++t)
        xi_cur[t] = XI[256 * (t >> 1) + rbase + 16 * (t & 1) + col];

    for (int n = 0; n < N_; ++n) {
        const half_t* hcur = hhb + (n & 1) * 256;

        // prefetch next step's XI (hides under this step's MFMA chain)
        float xi_nxt[8];
        if (n + 1 < N_) {
#pragma unroll
            for (int t = 0; t < 8; ++t)
                xi_nxt[t] = XI[(size_t)(n + 1) * 1024 + 256 * (t >> 1) + rbase + 16 * (t & 1) + col];
        } else {
#pragma unroll
            for (int t = 0; t < 8; ++t) xi_nxt[t] = 0.f;
        }

        float pre[8];   // gate pre-activations, filled half-pass by half-pass
#pragma unroll
        for (int half = 0; half < 2; ++half) {
            const int tb = half * 4;
            f32x4 D[4];
#pragma unroll
            for (int t = 0; t < 4; ++t) {
                const float x = xi_cur[tb + t];
                D[t] = f32x4{x, x, x, x};
            }
#pragma unroll
            for (int kt = 0; kt < 6; ++kt) {     // resident K-tiles
                f16x8 a = *(const f16x8*)(hcur + kt * 32 + quad * 8);
#pragma unroll
                for (int t = 0; t < 4; ++t)
                    D[t] = MFMA16x16x32F16(a, bfrag[tb + t][kt], D[t]);
            }
#pragma unroll
            for (int ktp = 0; ktp < 2; ++ktp) {  // streamed K-tiles (LDS b128)
                f16x8 a = *(const f16x8*)(hcur + 192 + ktp * 32 + quad * 8);
#pragma unroll
                for (int t = 0; t < 4; ++t) {
                    const int tt = tb + t;
                    const int row = 256 * (tt >> 1) + rbase + 16 * (tt & 1) + col;
                    f16x8 b = __builtin_bit_cast(f16x8, tail[quad * 2048 + ktp * 1024 + row]);
                    D[t] = MFMA16x16x32F16(a, b, D[t]);
                }
            }
#pragma unroll
            for (int t = 0; t < 4; ++t) pre[tb + t] = D[t].x;
        }

        // gates: t = g*2+s -> unit u0 uses t{0,2,4,6}, u1 uses t{1,3,5,7}
        float gi0 = sigmoidf_(pre[0]);
        float gf0 = sigmoidf_(pre[2]);
        float gg0 = tanhf_   (pre[4]);
        float go0 = sigmoidf_(pre[6]);
        c0 = gf0 * c0 + gi0 * gg0;
        float h0 = go0 * tanhf_(c0);

        float gi1 = sigmoidf_(pre[1]);
        float gf1 = sigmoidf_(pre[3]);
        float gg1 = tanhf_   (pre[5]);
        float go1 = sigmoidf_(pre[7]);
        c1 = gf1 * c1 + gi1 * gg1;
        float h1 = go1 * tanhf_(c1);

        half_t* hnxt = hhb + ((n + 1) & 1) * 256;
        if (quad == 0) {
            hnxt[u0] = (half_t)h0;
            hnxt[u1] = (half_t)h1;
            outs[(size_t)n * H_ + u0] = h0;
            outs[(size_t)n * H_ + u1] = h1;
        }
        __syncthreads();   // h(n+1) visible; buffer n free for step n+1 write
#pragma unroll
        for (int t = 0; t < 8; ++t) xi_cur[t] = xi_nxt[t];
    }
}

// ------------------------- final linear head -------------------------------
__global__ __launch_bounds__(256) void k_final(
    const float* __restrict__ outs, const float* __restrict__ Wl,
    const float* __restrict__ bl, float* __restrict__ y)
{
    const int lane = threadIdx.x & 63;
    const int g = threadIdx.x >> 6;
    const int n = blockIdx.x * 4 + g;
    const float* row = outs + (size_t)n * H_;
    float s = row[lane] * Wl[lane] + row[64 + lane] * Wl[64 + lane]
            + row[128 + lane] * Wl[128 + lane] + row[192 + lane] * Wl[192 + lane];
#pragma unroll
    for (int off = 32; off > 0; off >>= 1) s += __shfl_down(s, off, 64);
    if (lane == 0) y[n] = s + bl[0];
}

// ---------------------------------------------------------------------------
extern "C" void kernel_launch(void* const* d_in, const int* in_sizes, int n_in,
                              void* d_out, int out_size, void* d_ws, size_t ws_size,
                              hipStream_t stream)
{
    const float* tokens = (const float*)d_in[0];
    const int*   lengths= (const int*)  d_in[1];
    const float* Wih_t  = (const float*)d_in[2];
    const float* Whh_t  = (const float*)d_in[3];
    const float* bih_t  = (const float*)d_in[4];
    const float* bhh_t  = (const float*)d_in[5];
    const float* Wih_i  = (const float*)d_in[6];
    const float* Whh_i  = (const float*)d_in[7];
    const float* bih_i  = (const float*)d_in[8];
    const float* bhh_i  = (const float*)d_in[9];
    const float* Wl     = (const float*)d_in[10];
    const float* bl     = (const float*)d_in[11];
    float* out = (float*)d_out;

    char* ws = (char*)d_ws;
    float*  embeds = (float*) (ws);                                // 8 MB
    float*  XI     = (float*) (ws + (size_t)8  * 1024 * 1024);     // 32 MB
    float*  outs   = (float*) (ws + (size_t)40 * 1024 * 1024);     // 8 MB
    float4* WcatT  = (float4*)(ws + (size_t)48 * 1024 * 1024);     // 2 MB
    float4* WiT    = (float4*)(ws + (size_t)50 * 1024 * 1024);     // 1 MB

    (void)hipFuncSetAttribute((const void*)k_seq_lstm,
        hipFuncAttributeMaxDynamicSharedMemorySize, SMEM_SEQ);

    k_transpose_cat<<<512,  256, 0, stream>>>(Wih_t, Whh_t, WcatT);
    k_transpose_i  <<<256,  256, 0, stream>>>(Wih_i, WiT);
    k_token_lstm   <<<1024, 256, 0, stream>>>(tokens, lengths, WcatT, bih_t, bhh_t, embeds);
    k_xi           <<<512,  256, 0, stream>>>(embeds, WiT, bih_i, bhh_i, XI);
    k_seq_lstm     <<<1,    512, SMEM_SEQ, stream>>>(XI, Whh_i, outs);
    k_final        <<<2048, 256, 0, stream>>>(outs, Wl, bl, out);
}